// Round 3
// baseline (417.745 us; speedup 1.0000x reference)
//
#include <hip/hip_runtime.h>
#include <math.h>

typedef _Float16 f16x8 __attribute__((ext_vector_type(8)));
typedef float f32x4 __attribute__((ext_vector_type(4)));

// Problem constants
#define NROWS 32768   // 8*4096 input rows
#define KEMB  8192    // codebook entries
// DIM = 64

#define DECAYF 0.99f
#define OMDF   0.01f

// d_out layout (floats), reference return order
#define OUT_Q    0          // quantized, 2097152
#define OUT_LOSS 2097152    // vq_loss, 1
#define OUT_IDX  2097153    // idx (as float), 32768
#define OUT_PERP 2129921    // perplexity, 1
#define OUT_NW   2129922    // new_weight, 524288
#define OUT_NCC  2654210    // new_cc, 8192
#define OUT_NWS  2662402    // new_ws, 524288

// d_ws layout (4-byte units)
#define WS_N      0
#define WS_ENT    1
#define WS_LOSS   2
#define WS_TICKET 3
#define WS_COUNTS 4                    // 8192 floats (atomic)
#define WS_EMB    8196                 // 524288 floats (atomic)
#define WS_IDX    532484               // 32768 ints
#define WS_W2H    565252               // 8192 floats (= ||w||^2 / 2)
#define WS_WFRAG  573444               // 524288 f32 units = 2 MB f16 frag image
#define WS_ZERO_UNITS 532484           // scalars+ticket+counts+emb

__device__ __forceinline__ float sq_rn(float v) { return __fmul_rn(v, v); }

// numpy pairwise_sum order for 64 contiguous squared values
__device__ __forceinline__ float npsumsq64(const float* vbuf) {
  float a[8];
#pragma unroll
  for (int j = 0; j < 8; ++j) a[j] = sq_rn(vbuf[j]);
#pragma unroll
  for (int m = 1; m < 8; ++m)
#pragma unroll
    for (int j = 0; j < 8; ++j) a[j] = __fadd_rn(a[j], sq_rn(vbuf[m*8 + j]));
  return __fadd_rn(__fadd_rn(__fadd_rn(a[0],a[1]), __fadd_rn(a[2],a[3])),
                   __fadd_rn(__fadd_rn(a[4],a[5]), __fadd_rn(a[6],a[7])));
}

// split a float into (hi, lo) fp16 pair; hi+lo reproduces x to ~22 bits
__device__ __forceinline__ void split_f16(float x, _Float16& hi, _Float16& lo) {
  hi = (_Float16)x;
  float r = __fsub_rn(x, (float)hi);   // exact (Sterbenz)
  lo = (_Float16)r;
}

// async global->LDS, 16B per lane; LDS dest = wave-uniform base + lane*16
__device__ __forceinline__ void async16(const void* g, void* l) {
  __builtin_amdgcn_global_load_lds(
      (const __attribute__((address_space(1))) unsigned int*)g,
      (__attribute__((address_space(3))) unsigned int*)l, 16, 0, 0);
}

// prep: w2h[k] = 0.5*||w_k||^2 (numpy order), and W -> fragment-image f16 hi/lo.
// 73728 threads: [0,8192) w2h, [8192, 8192+65536) frag granules.
__global__ __launch_bounds__(256) void prep_kernel(const float* __restrict__ wg,
                                                   float* __restrict__ ws) {
  const int tid = blockIdx.x * 256 + threadIdx.x;
  if (tid < KEMB) {
    const float* src = wg + (size_t)tid * 64;
    float vbuf[64];
#pragma unroll
    for (int f = 0; f < 16; ++f) {
      float4 v = *(const float4*)(src + f*4);
      vbuf[f*4+0]=v.x; vbuf[f*4+1]=v.y; vbuf[f*4+2]=v.z; vbuf[f*4+3]=v.w;
    }
    ws[WS_W2H + tid] = __fmul_rn(0.5f, npsumsq64(vbuf));
  } else if (tid < KEMB + 65536) {
    const int u = tid - KEMB;            // granule: code K, dims g*8..g*8+7
    const int K = u >> 3, g = u & 7;
    const int n = K & 15, P = K >> 4;    // global panel 0..511
    const int quad = g & 3, shi = g >> 2;
    const int slot = quad*16 + n;
    const float* src = wg + (size_t)K*64 + g*8;
    float4 v0 = *(const float4*)src, v1 = *(const float4*)(src + 4);
    float vv[8] = {v0.x,v0.y,v0.z,v0.w,v1.x,v1.y,v1.z,v1.w};
    f16x8 hi, lo;
#pragma unroll
    for (int j = 0; j < 8; ++j) { _Float16 h, l; split_f16(vv[j], h, l); hi[j]=h; lo[j]=l; }
    _Float16* wf = (_Float16*)(ws + WS_WFRAG);
    *(f16x8*)&wf[((size_t)(P*4 + shi)*64 + slot)*8]     = hi;
    *(f16x8*)&wf[((size_t)(P*4 + 2 + shi)*64 + slot)*8] = lo;
  }
}

// argmin: 128 rows/block, 64 chunks of 128 codes, double-buffered LDS staging
// of the pre-built W-frag image. 512 threads = 8 waves (rg2 x cg4), wave tile
// 64 rows x 32 codes. dist = w2h - dot via negated-X MFMA with C=w2h.
__global__ __launch_bounds__(512, 2) void argmin_kernel(const float* __restrict__ xg,
                                                        float* __restrict__ out,
                                                        float* __restrict__ ws) {
  __shared__ __align__(16) _Float16 xp[8*4*64*8];       // 32 KB, X frags (negated)
  __shared__ __align__(16) _Float16 wp[2][8*4*64*8];    // 2 x 32 KB, W frag dbuf
  __shared__ float w2s[2][128];
  __shared__ float md[128*4];
  __shared__ int   mk[128*4];
  __shared__ int   bkL[128];

  const int t    = threadIdx.x;
  const int lane = t & 63, wv = t >> 6;
  const int quad = lane >> 4, n16 = lane & 15;
  const int rg = wv >> 2, cg = wv & 3;
  const int row0 = blockIdx.x * 128;
  const _Float16* wfrag = (const _Float16*)(ws + WS_WFRAG);
  const float* w2hg = ws + WS_W2H;

  // ---- prologue: convert X tile (NEGATED) into fragment layout ----
#pragma unroll
  for (int it = 0; it < 2; ++it) {
    const int u  = t + 512*it;          // < 1024 granules
    const int rp = u >> 7, n = (u >> 3) & 15, g = u & 7;
    const float* src = xg + (size_t)(row0 + rp*16 + n)*64 + g*8;
    float4 v0 = *(const float4*)src, v1 = *(const float4*)(src + 4);
    float vv[8] = {v0.x,v0.y,v0.z,v0.w,v1.x,v1.y,v1.z,v1.w};
    f16x8 hi, lo;
#pragma unroll
    for (int j = 0; j < 8; ++j) { _Float16 h, l; split_f16(-vv[j], h, l); hi[j]=h; lo[j]=l; }
    const int slot = (g&3)*16 + n, shi = g >> 2;
    *(f16x8*)&xp[(((rp*4) + shi)*64 + slot)*8]     = hi;
    *(f16x8*)&xp[(((rp*4) + 2 + shi)*64 + slot)*8] = lo;
  }

  // ---- stage chunk 0 into buf 0 ----
  {
    const char* g = (const char*)wfrag;
#pragma unroll
    for (int i = 0; i < 4; ++i)
      async16(g + (i*8 + wv)*1024 + lane*16, (char*)&wp[0][0] + (i*8 + wv)*1024);
    if (t < 128) w2s[0][t] = w2hg[t];
  }
  __syncthreads();

  // A-frags resident in registers for the whole loop
  f16x8 a[4][4];
#pragma unroll
  for (int rt = 0; rt < 4; ++rt)
#pragma unroll
    for (int s = 0; s < 4; ++s)
      a[rt][s] = *(const f16x8*)&xp[(((rg*4+rt)*4 + s)*64 + lane)*8];

  float best[16]; int bestk[16];
#pragma unroll
  for (int i = 0; i < 16; ++i) { best[i] = INFINITY; bestk[i] = 0; }

  for (int c = 0; c < 64; ++c) {
    const int b = c & 1;
    if (c < 63) {   // prefetch chunk c+1 into the other buffer
      const char* g = (const char*)wfrag + (size_t)(c+1)*32768;
#pragma unroll
      for (int i = 0; i < 4; ++i)
        async16(g + (i*8 + wv)*1024 + lane*16, (char*)&wp[b^1][0] + (i*8 + wv)*1024);
      if (t < 128) w2s[b^1][t] = w2hg[(c+1)*128 + t];
    }
    const int k0 = c * 128;
#pragma unroll
    for (int p = 0; p < 2; ++p) {
      const int pl = cg*2 + p;
      f16x8 b0 = *(const f16x8*)&wp[b][((pl*4+0)*64 + lane)*8];
      f16x8 b1 = *(const f16x8*)&wp[b][((pl*4+1)*64 + lane)*8];
      f16x8 b2 = *(const f16x8*)&wp[b][((pl*4+2)*64 + lane)*8];
      f16x8 b3 = *(const f16x8*)&wp[b][((pl*4+3)*64 + lane)*8];
      const float w2hv = w2s[b][pl*16 + n16];
      const f32x4 cin = {w2hv, w2hv, w2hv, w2hv};
      f32x4 acc[4];
      // acc = w2h + sum of (-x)*w products (8 terms), rt-interleaved
#pragma unroll
      for (int rt = 0; rt < 4; ++rt) acc[rt] = __builtin_amdgcn_mfma_f32_16x16x32_f16(a[rt][0], b0, cin, 0,0,0);
#pragma unroll
      for (int rt = 0; rt < 4; ++rt) acc[rt] = __builtin_amdgcn_mfma_f32_16x16x32_f16(a[rt][1], b1, acc[rt], 0,0,0);
#pragma unroll
      for (int rt = 0; rt < 4; ++rt) acc[rt] = __builtin_amdgcn_mfma_f32_16x16x32_f16(a[rt][2], b0, acc[rt], 0,0,0);
#pragma unroll
      for (int rt = 0; rt < 4; ++rt) acc[rt] = __builtin_amdgcn_mfma_f32_16x16x32_f16(a[rt][3], b1, acc[rt], 0,0,0);
#pragma unroll
      for (int rt = 0; rt < 4; ++rt) acc[rt] = __builtin_amdgcn_mfma_f32_16x16x32_f16(a[rt][0], b2, acc[rt], 0,0,0);
#pragma unroll
      for (int rt = 0; rt < 4; ++rt) acc[rt] = __builtin_amdgcn_mfma_f32_16x16x32_f16(a[rt][1], b3, acc[rt], 0,0,0);
#pragma unroll
      for (int rt = 0; rt < 4; ++rt) acc[rt] = __builtin_amdgcn_mfma_f32_16x16x32_f16(a[rt][2], b2, acc[rt], 0,0,0);
#pragma unroll
      for (int rt = 0; rt < 4; ++rt) acc[rt] = __builtin_amdgcn_mfma_f32_16x16x32_f16(a[rt][3], b3, acc[rt], 0,0,0);

      const int kk = k0 + pl*16 + n16;   // ascending over c, p => lowest-k ties
#pragma unroll
      for (int rt = 0; rt < 4; ++rt)
#pragma unroll
        for (int reg = 0; reg < 4; ++reg) {
          const float dist = acc[rt][reg];
          const int bi = rt*4 + reg;
          if (dist < best[bi]) { best[bi] = dist; bestk[bi] = kk; }
        }
    }
    __syncthreads();   // drains prefetch; frees wp[b] for c+2
  }

  // ---- cross-lane merge within 16-lane col groups (lexicographic (d,k)) ----
#pragma unroll
  for (int bi = 0; bi < 16; ++bi) {
    float bd = best[bi]; int bk = bestk[bi];
#pragma unroll
    for (int m = 1; m < 16; m <<= 1) {
      const float od = __shfl_xor(bd, m, 64);
      const int   ok = __shfl_xor(bk, m, 64);
      if (od < bd || (od == bd && ok < bk)) { bd = od; bk = ok; }
    }
    best[bi] = bd; bestk[bi] = bk;
  }
  if (n16 == 0) {
#pragma unroll
    for (int rt = 0; rt < 4; ++rt)
#pragma unroll
      for (int reg = 0; reg < 4; ++reg) {
        const int row = rg*64 + rt*16 + quad*4 + reg;
        md[row*4 + cg] = best[rt*4+reg];
        mk[row*4 + cg] = bestk[rt*4+reg];
      }
  }
  __syncthreads();

  if (t < 128) {
    const int row = t;
    float bd = md[row*4]; int bk = mk[row*4];
#pragma unroll
    for (int u = 1; u < 4; ++u) {
      const float d2 = md[row*4 + u]; const int k2 = mk[row*4 + u];
      if (d2 < bd || (d2 == bd && k2 < bk)) { bd = d2; bk = k2; }
    }
    out[OUT_IDX + row0 + row] = (float)bk;
    ((int*)ws)[WS_IDX + row0 + row] = bk;
    bkL[row] = bk;
    atomicAdd(&ws[WS_COUNTS + bk], 1.0f);
  }
  __syncthreads();

  // ---- EMA segment-sum atomics (x re-read from global, coalesced) ----
#pragma unroll 4
  for (int r8 = 0; r8 < 16; ++r8) {
    const int row = r8*8 + (t >> 6);
    const int d = t & 63;
    const int bk = bkL[row];
    atomicAdd(&ws[WS_EMB + (size_t)bk*64 + d], xg[(size_t)(row0 + row)*64 + d]);
  }
}

__global__ __launch_bounds__(256) void stats_kernel(const float* __restrict__ cc,
                                                    float* __restrict__ out,
                                                    float* __restrict__ ws) {
  const int k = blockIdx.x * 256 + threadIdx.x;
  const float cnt = ws[WS_COUNTS + k];
  const float ncc = __fadd_rn(__fmul_rn(DECAYF, cc[k]), __fmul_rn(OMDF, cnt));
  out[OUT_NCC + k] = ncc;
  const float p = cnt * (1.0f/32768.0f);
  const float ent = __fmul_rn(p, logf(__fadd_rn(p, 1e-10f)));
  float v1 = ncc, v2 = ent;
#pragma unroll
  for (int off = 32; off > 0; off >>= 1) {
    v1 += __shfl_down(v1, off);
    v2 += __shfl_down(v2, off);
  }
  __shared__ float s1[4], s2[4];
  const int lane = threadIdx.x & 63, wid = threadIdx.x >> 6;
  if (lane == 0) { s1[wid] = v1; s2[wid] = v2; }
  __syncthreads();
  if (threadIdx.x == 0) {
    atomicAdd(&ws[WS_N],   (s1[0]+s1[1]) + (s1[2]+s1[3]));
    atomicAdd(&ws[WS_ENT], (s2[0]+s2[1]) + (s2[2]+s2[3]));
  }
}

__global__ __launch_bounds__(256) void update_kernel(const float* __restrict__ ws0,
                                                     float* __restrict__ out,
                                                     float* __restrict__ ws) {
  const int e = blockIdx.x * 256 + threadIdx.x;  // < 524288
  const int k = e >> 6;
  const float nws = __fadd_rn(__fmul_rn(DECAYF, ws0[e]), __fmul_rn(OMDF, ws[WS_EMB + e]));
  out[OUT_NWS + e] = nws;
  const float n = ws[WS_N];
  const float ncc = out[OUT_NCC + k];
  const float smoothed = __fmul_rn(__fadd_rn(ncc, 1e-5f) / __fadd_rn(n, 0.08192f), n);
  out[OUT_NW + e] = nws / smoothed;
  if (e == 0) out[OUT_PERP] = expf(-ws[WS_ENT]);
}

__global__ __launch_bounds__(256) void quant_kernel(const float* __restrict__ xg,
                                                    float* __restrict__ out,
                                                    float* __restrict__ ws) {
  const int e = blockIdx.x * 256 + threadIdx.x;  // < 2097152
  const int row = e >> 6, d = e & 63;
  const int k = ((const int*)ws)[WS_IDX + row];
  const float q = out[OUT_NW + (size_t)k*64 + d];
  const float x = xg[e];
  const float df = __fsub_rn(q, x);
  out[OUT_Q + e] = __fadd_rn(x, df);
  float v = __fmul_rn(df, df);
#pragma unroll
  for (int off = 32; off > 0; off >>= 1) v += __shfl_down(v, off);
  __shared__ float sm[4];
  const int lane = threadIdx.x & 63, wid = threadIdx.x >> 6;
  if (lane == 0) sm[wid] = v;
  __syncthreads();
  if (threadIdx.x == 0) {
    atomicAdd(&ws[WS_LOSS], (sm[0]+sm[1]) + (sm[2]+sm[3]));
    __threadfence();
    if (atomicAdd(&((int*)ws)[WS_TICKET], 1) == 8191) {   // last block finalizes
      const float loss = atomicAdd(&ws[WS_LOSS], 0.0f);
      out[OUT_LOSS] = __fmul_rn(0.25f, loss / 2097152.0f);
    }
  }
}

extern "C" void kernel_launch(void* const* d_in, const int* in_sizes, int n_in,
                              void* d_out, int out_size, void* d_ws, size_t ws_size,
                              hipStream_t stream) {
  (void)in_sizes; (void)n_in; (void)out_size; (void)ws_size;
  const float* x   = (const float*)d_in[0];
  const float* w   = (const float*)d_in[1];
  const float* cc  = (const float*)d_in[2];
  const float* ws0 = (const float*)d_in[3];
  float* out = (float*)d_out;
  float* ws  = (float*)d_ws;

  hipMemsetAsync(d_ws, 0, (size_t)WS_ZERO_UNITS * 4, stream);
  hipLaunchKernelGGL(prep_kernel,   dim3(288),  dim3(256), 0, stream, w, ws);
  hipLaunchKernelGGL(argmin_kernel, dim3(256),  dim3(512), 0, stream, x, out, ws);
  hipLaunchKernelGGL(stats_kernel,  dim3(32),   dim3(256), 0, stream, cc, out, ws);
  hipLaunchKernelGGL(update_kernel, dim3(2048), dim3(256), 0, stream, ws0, out, ws);
  hipLaunchKernelGGL(quant_kernel,  dim3(8192), dim3(256), 0, stream, x, out, ws);
}

// Round 4
// 243.536 us; speedup vs baseline: 1.7153x; 1.7153x over previous
//
#include <hip/hip_runtime.h>
#include <math.h>

typedef _Float16 f16x8 __attribute__((ext_vector_type(8)));
typedef float f32x4 __attribute__((ext_vector_type(4)));

// Problem constants
#define NROWS 32768   // 8*4096 input rows
#define KEMB  8192    // codebook entries
// DIM = 64

#define DECAYF 0.99f
#define OMDF   0.01f

// d_out layout (floats), reference return order
#define OUT_Q    0          // quantized, 2097152
#define OUT_LOSS 2097152    // vq_loss, 1
#define OUT_IDX  2097153    // idx (as float), 32768
#define OUT_PERP 2129921    // perplexity, 1
#define OUT_NW   2129922    // new_weight, 524288
#define OUT_NCC  2654210    // new_cc, 8192
#define OUT_NWS  2662402    // new_ws, 524288

// d_ws layout (4-byte units)
#define WS_N      0
#define WS_ENT    1
#define WS_COUNTS 4                    // 8192 floats (argmin atomics; REUSED as quant partials after stats)
#define WS_EMB    8196                 // 524288 floats (atomic)
#define WS_IDX    532484               // 32768 ints
#define WS_W2H    565252               // 8192 floats (= ||w||^2 / 2)
#define WS_WFRAG  573444               // 524288 f32 units = 2 MB f16 frag image
#define WS_ZERO_UNITS 532484           // scalars+counts+emb

__device__ __forceinline__ float sq_rn(float v) { return __fmul_rn(v, v); }

// numpy pairwise_sum order for 64 contiguous squared values
__device__ __forceinline__ float npsumsq64(const float* vbuf) {
  float a[8];
#pragma unroll
  for (int j = 0; j < 8; ++j) a[j] = sq_rn(vbuf[j]);
#pragma unroll
  for (int m = 1; m < 8; ++m)
#pragma unroll
    for (int j = 0; j < 8; ++j) a[j] = __fadd_rn(a[j], sq_rn(vbuf[m*8 + j]));
  return __fadd_rn(__fadd_rn(__fadd_rn(a[0],a[1]), __fadd_rn(a[2],a[3])),
                   __fadd_rn(__fadd_rn(a[4],a[5]), __fadd_rn(a[6],a[7])));
}

// split a float into (hi, lo) fp16 pair; hi+lo reproduces x to ~22 bits
__device__ __forceinline__ void split_f16(float x, _Float16& hi, _Float16& lo) {
  hi = (_Float16)x;
  float r = __fsub_rn(x, (float)hi);   // exact (Sterbenz)
  lo = (_Float16)r;
}

// async global->LDS, 16B/lane; LDS dest = wave-uniform base + lane*16
__device__ __forceinline__ void async16(const void* g, void* l) {
  __builtin_amdgcn_global_load_lds(
      (const __attribute__((address_space(1))) unsigned int*)g,
      (__attribute__((address_space(3))) unsigned int*)l, 16, 0, 0);
}

// prep: w2h[k] = 0.5*||w_k||^2 (numpy order), W -> fragment-image f16 hi/lo
__global__ __launch_bounds__(256) void prep_kernel(const float* __restrict__ wg,
                                                   float* __restrict__ ws) {
  const int tid = blockIdx.x * 256 + threadIdx.x;
  if (tid < KEMB) {
    const float* src = wg + (size_t)tid * 64;
    float vbuf[64];
#pragma unroll
    for (int f = 0; f < 16; ++f) {
      float4 v = *(const float4*)(src + f*4);
      vbuf[f*4+0]=v.x; vbuf[f*4+1]=v.y; vbuf[f*4+2]=v.z; vbuf[f*4+3]=v.w;
    }
    ws[WS_W2H + tid] = __fmul_rn(0.5f, npsumsq64(vbuf));
  } else if (tid < KEMB + 65536) {
    const int u = tid - KEMB;            // granule: code K, dims g*8..g*8+7
    const int K = u >> 3, g = u & 7;
    const int n = K & 15, P = K >> 4;    // global panel 0..511
    const int slot = (g&3)*16 + n, shi = g >> 2;
    const float* src = wg + (size_t)K*64 + g*8;
    float4 v0 = *(const float4*)src, v1 = *(const float4*)(src + 4);
    float vv[8] = {v0.x,v0.y,v0.z,v0.w,v1.x,v1.y,v1.z,v1.w};
    f16x8 hi, lo;
#pragma unroll
    for (int j = 0; j < 8; ++j) { _Float16 h, l; split_f16(vv[j], h, l); hi[j]=h; lo[j]=l; }
    _Float16* wf = (_Float16*)(ws + WS_WFRAG);
    *(f16x8*)&wf[((size_t)(P*4 + shi)*64 + slot)*8]     = hi;
    *(f16x8*)&wf[((size_t)(P*4 + 2 + shi)*64 + slot)*8] = lo;
  }
}

// argmin: 512 blocks x 256 threads (4 waves), 64 rows/block, 128 chunks of
// 64 codes, double-buffered global_load_lds staging of W-frag image.
// ~50.5 KB LDS -> 3 blocks/CU (independent barriers = latency overlap).
// dist = w2h - dot via negated-X MFMA with C = w2h/ (w2h seeds accumulator).
__global__ __launch_bounds__(256) void argmin_kernel(const float* __restrict__ xg,
                                                     float* __restrict__ out,
                                                     float* __restrict__ ws) {
  __shared__ __align__(16) _Float16 xp[4*4*64*8];       // 16 KB, X frags (negated)
  __shared__ __align__(16) _Float16 wp[2][4*4*64*8];    // 2 x 16 KB, W frag dbuf
  __shared__ float w2s[2][64];
  __shared__ float md[64*4];
  __shared__ int   mk[64*4];

  const int t    = threadIdx.x;
  const int lane = t & 63, wv = t >> 6;          // 4 waves; wave = col group
  const int quad = lane >> 4, n16 = lane & 15;
  const int row0 = blockIdx.x * 64;
  const _Float16* wfrag = (const _Float16*)(ws + WS_WFRAG);
  const float* w2hg = ws + WS_W2H;

  // ---- prologue: convert X tile (NEGATED) into fragment layout ----
#pragma unroll
  for (int it = 0; it < 2; ++it) {
    const int u  = t + 256*it;          // < 512 granules
    const int rp = u >> 7, n = (u >> 3) & 15, g = u & 7;
    const float* src = xg + (size_t)(row0 + rp*16 + n)*64 + g*8;
    float4 v0 = *(const float4*)src, v1 = *(const float4*)(src + 4);
    float vv[8] = {v0.x,v0.y,v0.z,v0.w,v1.x,v1.y,v1.z,v1.w};
    f16x8 hi, lo;
#pragma unroll
    for (int j = 0; j < 8; ++j) { _Float16 h, l; split_f16(-vv[j], h, l); hi[j]=h; lo[j]=l; }
    const int slot = (g&3)*16 + n, shi = g >> 2;
    *(f16x8*)&xp[(((rp*4) + shi)*64 + slot)*8]     = hi;
    *(f16x8*)&xp[(((rp*4) + 2 + shi)*64 + slot)*8] = lo;
  }

  // ---- stage chunk 0 into buf 0 (16 KB) ----
  {
    const char* g = (const char*)wfrag;
#pragma unroll
    for (int i = 0; i < 4; ++i)
      async16(g + (i*4 + wv)*1024 + lane*16, (char*)&wp[0][0] + (i*4 + wv)*1024);
    if (t < 64) w2s[0][t] = w2hg[t];
  }
  __syncthreads();

  // A-frags resident (all 64 rows per wave): 16 x f16x8 = 64 VGPRs
  f16x8 a[4][4];
#pragma unroll
  for (int rt = 0; rt < 4; ++rt)
#pragma unroll
    for (int s = 0; s < 4; ++s)
      a[rt][s] = *(const f16x8*)&xp[(((rt*4 + s)*64 + lane))*8];

  float best[16]; int bestk[16];
#pragma unroll
  for (int i = 0; i < 16; ++i) { best[i] = INFINITY; bestk[i] = 0; }

  for (int c = 0; c < 128; ++c) {
    const int b = c & 1;
    if (c < 127) {   // prefetch chunk c+1 into the other buffer
      const char* g = (const char*)wfrag + (size_t)(c+1)*16384;
#pragma unroll
      for (int i = 0; i < 4; ++i)
        async16(g + (i*4 + wv)*1024 + lane*16, (char*)&wp[b^1][0] + (i*4 + wv)*1024);
      if (t < 64) w2s[b^1][t] = w2hg[(c+1)*64 + t];
    }
    // ---- this wave's panel: 16 codes x 64 rows ----
    f16x8 b0 = *(const f16x8*)&wp[b][((wv*4+0)*64 + lane)*8];
    f16x8 b1 = *(const f16x8*)&wp[b][((wv*4+1)*64 + lane)*8];
    f16x8 b2 = *(const f16x8*)&wp[b][((wv*4+2)*64 + lane)*8];
    f16x8 b3 = *(const f16x8*)&wp[b][((wv*4+3)*64 + lane)*8];
    const float w2hv = w2s[b][wv*16 + n16];
    const f32x4 cin = {w2hv, w2hv, w2hv, w2hv};
    f32x4 acc[4];
    // acc = w2h + sum of (-x)*w products (8 terms), rt-interleaved
#pragma unroll
    for (int rt = 0; rt < 4; ++rt) acc[rt] = __builtin_amdgcn_mfma_f32_16x16x32_f16(a[rt][0], b0, cin, 0,0,0);
#pragma unroll
    for (int rt = 0; rt < 4; ++rt) acc[rt] = __builtin_amdgcn_mfma_f32_16x16x32_f16(a[rt][1], b1, acc[rt], 0,0,0);
#pragma unroll
    for (int rt = 0; rt < 4; ++rt) acc[rt] = __builtin_amdgcn_mfma_f32_16x16x32_f16(a[rt][2], b0, acc[rt], 0,0,0);
#pragma unroll
    for (int rt = 0; rt < 4; ++rt) acc[rt] = __builtin_amdgcn_mfma_f32_16x16x32_f16(a[rt][3], b1, acc[rt], 0,0,0);
#pragma unroll
    for (int rt = 0; rt < 4; ++rt) acc[rt] = __builtin_amdgcn_mfma_f32_16x16x32_f16(a[rt][0], b2, acc[rt], 0,0,0);
#pragma unroll
    for (int rt = 0; rt < 4; ++rt) acc[rt] = __builtin_amdgcn_mfma_f32_16x16x32_f16(a[rt][1], b3, acc[rt], 0,0,0);
#pragma unroll
    for (int rt = 0; rt < 4; ++rt) acc[rt] = __builtin_amdgcn_mfma_f32_16x16x32_f16(a[rt][2], b2, acc[rt], 0,0,0);
#pragma unroll
    for (int rt = 0; rt < 4; ++rt) acc[rt] = __builtin_amdgcn_mfma_f32_16x16x32_f16(a[rt][3], b3, acc[rt], 0,0,0);

    const int kk = c*64 + wv*16 + n16;   // ascending over c => lowest-k ties
#pragma unroll
    for (int rt = 0; rt < 4; ++rt)
#pragma unroll
      for (int reg = 0; reg < 4; ++reg) {
        const float dist = acc[rt][reg];
        const int bi = rt*4 + reg;
        if (dist < best[bi]) { best[bi] = dist; bestk[bi] = kk; }
      }
    __syncthreads();   // drains prefetch; frees wp[b] for c+2
  }

  // ---- merge 16 code-lanes per quad (lexicographic (d,k)) ----
#pragma unroll
  for (int bi = 0; bi < 16; ++bi) {
    float bd = best[bi]; int bk = bestk[bi];
#pragma unroll
    for (int m = 1; m < 16; m <<= 1) {
      const float od = __shfl_xor(bd, m, 64);
      const int   ok = __shfl_xor(bk, m, 64);
      if (od < bd || (od == bd && ok < bk)) { bd = od; bk = ok; }
    }
    best[bi] = bd; bestk[bi] = bk;
  }
  if (n16 == 0) {
#pragma unroll
    for (int rt = 0; rt < 4; ++rt)
#pragma unroll
      for (int reg = 0; reg < 4; ++reg) {
        const int row = rt*16 + quad*4 + reg;
        md[row*4 + wv] = best[rt*4+reg];
        mk[row*4 + wv] = bestk[rt*4+reg];
      }
  }
  __syncthreads();

  if (t < 64) {
    const int row = t;
    float bd = md[row*4]; int bk = mk[row*4];
#pragma unroll
    for (int u = 1; u < 4; ++u) {
      const float d2 = md[row*4 + u]; const int k2 = mk[row*4 + u];
      if (d2 < bd || (d2 == bd && k2 < bk)) { bd = d2; bk = k2; }
    }
    out[OUT_IDX + row0 + row] = (float)bk;
    ((int*)ws)[WS_IDX + row0 + row] = bk;
    atomicAdd(&ws[WS_COUNTS + bk], 1.0f);
  }
}

// EMA segment-sum: 256 blocks x 256 threads; wave handles 32 rows.
// 2M distinct-address fp32 atomics, isolated for attribution.
__global__ __launch_bounds__(256) void ema_kernel(const float* __restrict__ xg,
                                                  float* __restrict__ ws) {
  const int lane = threadIdx.x & 63, wv = threadIdx.x >> 6;
  const int base = blockIdx.x * 128 + wv * 32;
  const int* idxb = (const int*)ws + WS_IDX;
#pragma unroll 4
  for (int r = 0; r < 32; ++r) {
    const int row = base + r;
    const int k = idxb[row];
    atomicAdd(&ws[WS_EMB + (size_t)k*64 + lane], xg[(size_t)row*64 + lane]);
  }
}

// stats: ONE block, no atomics. new_cc out; N and ENT scalars.
__global__ __launch_bounds__(256) void stats_kernel(const float* __restrict__ cc,
                                                    float* __restrict__ out,
                                                    float* __restrict__ ws) {
  const int t = threadIdx.x;
  float v1 = 0.0f, v2 = 0.0f;
#pragma unroll
  for (int i = 0; i < 32; ++i) {
    const int k = i*256 + t;
    const float cnt = ws[WS_COUNTS + k];
    const float ncc = __fadd_rn(__fmul_rn(DECAYF, cc[k]), __fmul_rn(OMDF, cnt));
    out[OUT_NCC + k] = ncc;
    const float p = cnt * (1.0f/32768.0f);
    v1 += ncc;
    v2 += __fmul_rn(p, logf(__fadd_rn(p, 1e-10f)));
  }
#pragma unroll
  for (int off = 32; off > 0; off >>= 1) {
    v1 += __shfl_down(v1, off);
    v2 += __shfl_down(v2, off);
  }
  __shared__ float s1[4], s2[4];
  const int lane = t & 63, wid = t >> 6;
  if (lane == 0) { s1[wid] = v1; s2[wid] = v2; }
  __syncthreads();
  if (t == 0) {
    ws[WS_N]   = (s1[0]+s1[1]) + (s1[2]+s1[3]);
    ws[WS_ENT] = (s2[0]+s2[1]) + (s2[2]+s2[3]);
  }
}

__global__ __launch_bounds__(256) void update_kernel(const float* __restrict__ ws0,
                                                     float* __restrict__ out,
                                                     float* __restrict__ ws) {
  const int e = blockIdx.x * 256 + threadIdx.x;  // < 524288
  const int k = e >> 6;
  const float nws = __fadd_rn(__fmul_rn(DECAYF, ws0[e]), __fmul_rn(OMDF, ws[WS_EMB + e]));
  out[OUT_NWS + e] = nws;
  const float n = ws[WS_N];
  const float ncc = out[OUT_NCC + k];
  const float smoothed = __fmul_rn(__fadd_rn(ncc, 1e-5f) / __fadd_rn(n, 0.08192f), n);
  out[OUT_NW + e] = nws / smoothed;
  if (e == 0) out[OUT_PERP] = expf(-ws[WS_ENT]);
}

// quant: 512 blocks x 256 threads x 4 float4; partial sums to DISTINCT slots
// (reuse WS_COUNTS -- already consumed by stats). No same-address atomics.
__global__ __launch_bounds__(256) void quant_kernel(const float* __restrict__ xg,
                                                    float* __restrict__ out,
                                                    float* __restrict__ ws) {
  const int t = threadIdx.x;
  const int* idxb = (const int*)ws + WS_IDX;
  float v = 0.0f;
#pragma unroll
  for (int j = 0; j < 4; ++j) {
    const int e4 = (j*512 + blockIdx.x)*256 + t;   // float4 index, coalesced
    const int row = e4 >> 4, d = (e4 & 15) * 4;
    const int k = idxb[row];
    const float* nw = out + OUT_NW + (size_t)k*64 + d;
    float2 q0 = *(const float2*)nw, q1 = *(const float2*)(nw + 2);  // 8B-aligned
    float4 x = *(const float4*)(xg + (size_t)e4*4);
    float qv[4] = {q0.x, q0.y, q1.x, q1.y};
    float xv[4] = {x.x, x.y, x.z, x.w};
    float4 o;
    float ov[4];
#pragma unroll
    for (int i = 0; i < 4; ++i) {
      const float df = __fsub_rn(qv[i], xv[i]);
      ov[i] = __fadd_rn(xv[i], df);
      v = fmaf(df, df, v);
    }
    o.x = ov[0]; o.y = ov[1]; o.z = ov[2]; o.w = ov[3];
    *(float4*)(out + OUT_Q + (size_t)e4*4) = o;
  }
#pragma unroll
  for (int off = 32; off > 0; off >>= 1) v += __shfl_down(v, off);
  __shared__ float sm[4];
  const int lane = t & 63, wid = t >> 6;
  if (lane == 0) sm[wid] = v;
  __syncthreads();
  if (t == 0) ws[WS_COUNTS + blockIdx.x] = (sm[0]+sm[1]) + (sm[2]+sm[3]);
}

__global__ void final_kernel(float* __restrict__ out, const float* __restrict__ ws) {
  const int t = threadIdx.x;   // 64 threads
  float v = 0.0f;
#pragma unroll
  for (int i = 0; i < 8; ++i) v += ws[WS_COUNTS + i*64 + t];
#pragma unroll
  for (int off = 32; off > 0; off >>= 1) v += __shfl_down(v, off);
  if (t == 0) out[OUT_LOSS] = __fmul_rn(0.25f, v / 2097152.0f);
}

extern "C" void kernel_launch(void* const* d_in, const int* in_sizes, int n_in,
                              void* d_out, int out_size, void* d_ws, size_t ws_size,
                              hipStream_t stream) {
  (void)in_sizes; (void)n_in; (void)out_size; (void)ws_size;
  const float* x   = (const float*)d_in[0];
  const float* w   = (const float*)d_in[1];
  const float* cc  = (const float*)d_in[2];
  const float* ws0 = (const float*)d_in[3];
  float* out = (float*)d_out;
  float* ws  = (float*)d_ws;

  hipMemsetAsync(d_ws, 0, (size_t)WS_ZERO_UNITS * 4, stream);
  hipLaunchKernelGGL(prep_kernel,   dim3(288),  dim3(256), 0, stream, w, ws);
  hipLaunchKernelGGL(argmin_kernel, dim3(512),  dim3(256), 0, stream, x, out, ws);
  hipLaunchKernelGGL(ema_kernel,    dim3(256),  dim3(256), 0, stream, x, ws);
  hipLaunchKernelGGL(stats_kernel,  dim3(1),    dim3(256), 0, stream, cc, out, ws);
  hipLaunchKernelGGL(update_kernel, dim3(2048), dim3(256), 0, stream, ws0, out, ws);
  hipLaunchKernelGGL(quant_kernel,  dim3(512),  dim3(256), 0, stream, x, out, ws);
  hipLaunchKernelGGL(final_kernel,  dim3(1),    dim3(64),  0, stream, out, ws);
}

// Round 5
// 211.130 us; speedup vs baseline: 1.9786x; 1.1535x over previous
//
#include <hip/hip_runtime.h>
#include <math.h>

typedef _Float16 f16x8 __attribute__((ext_vector_type(8)));
typedef float f32x4 __attribute__((ext_vector_type(4)));

// Problem constants
#define NROWS 32768   // 8*4096 input rows
#define KEMB  8192    // codebook entries
// DIM = 64

#define DECAYF 0.99f
#define OMDF   0.01f

// d_out layout (floats), reference return order
#define OUT_Q    0          // quantized, 2097152
#define OUT_LOSS 2097152    // vq_loss, 1
#define OUT_IDX  2097153    // idx (as float), 32768
#define OUT_PERP 2129921    // perplexity, 1
#define OUT_NW   2129922    // new_weight, 524288
#define OUT_NCC  2654210    // new_cc, 8192
#define OUT_NWS  2662402    // new_ws, 524288

// d_ws layout (4-byte units)
#define WS_N      0
#define WS_ENT    1
#define WS_COUNTS 4                    // 8192 floats (argmin atomics; reused as quant partials)
#define WS_EMB    8196                 // 524288 floats (atomic)
#define WS_IDX    532484               // 32768 ints
#define WS_W2H    565252               // 8192 floats (= ||w||^2 / 2)
#define WS_WFRAG  573444               // 524288 f32 units = 2 MB f16 frag image
#define WS_ZERO_UNITS 532484           // scalars+counts+emb

__device__ __forceinline__ float sq_rn(float v) { return __fmul_rn(v, v); }

// numpy pairwise_sum order for 64 contiguous squared values
__device__ __forceinline__ float npsumsq64(const float* vbuf) {
  float a[8];
#pragma unroll
  for (int j = 0; j < 8; ++j) a[j] = sq_rn(vbuf[j]);
#pragma unroll
  for (int m = 1; m < 8; ++m)
#pragma unroll
    for (int j = 0; j < 8; ++j) a[j] = __fadd_rn(a[j], sq_rn(vbuf[m*8 + j]));
  return __fadd_rn(__fadd_rn(__fadd_rn(a[0],a[1]), __fadd_rn(a[2],a[3])),
                   __fadd_rn(__fadd_rn(a[4],a[5]), __fadd_rn(a[6],a[7])));
}

// split a float into (hi, lo) fp16 pair; hi+lo reproduces x to ~22 bits
__device__ __forceinline__ void split_f16(float x, _Float16& hi, _Float16& lo) {
  hi = (_Float16)x;
  float r = __fsub_rn(x, (float)hi);   // exact (Sterbenz)
  lo = (_Float16)r;
}

// prep: w2h[k] = 0.5*||w_k||^2 (numpy order), W -> fragment-image f16 hi/lo.
// Image layout: frag(panel P, s, lane l) at wf[((P*4+s)*64+l)*8 .. +8];
// s=0,1 hi (K 0..31 / 32..63), s=2,3 lo. A per-lane dwordx4 load IS a B-frag.
__global__ __launch_bounds__(256) void prep_kernel(const float* __restrict__ wg,
                                                   float* __restrict__ ws) {
  const int tid = blockIdx.x * 256 + threadIdx.x;
  if (tid < KEMB) {
    const float* src = wg + (size_t)tid * 64;
    float vbuf[64];
#pragma unroll
    for (int f = 0; f < 16; ++f) {
      float4 v = *(const float4*)(src + f*4);
      vbuf[f*4+0]=v.x; vbuf[f*4+1]=v.y; vbuf[f*4+2]=v.z; vbuf[f*4+3]=v.w;
    }
    ws[WS_W2H + tid] = __fmul_rn(0.5f, npsumsq64(vbuf));
  } else if (tid < KEMB + 65536) {
    const int u = tid - KEMB;            // granule: code K, dims g*8..g*8+7
    const int K = u >> 3, g = u & 7;
    const int n = K & 15, P = K >> 4;    // global panel 0..511
    const int slot = (g&3)*16 + n, shi = g >> 2;
    const float* src = wg + (size_t)K*64 + g*8;
    float4 v0 = *(const float4*)src, v1 = *(const float4*)(src + 4);
    float vv[8] = {v0.x,v0.y,v0.z,v0.w,v1.x,v1.y,v1.z,v1.w};
    f16x8 hi, lo;
#pragma unroll
    for (int j = 0; j < 8; ++j) { _Float16 h, l; split_f16(vv[j], h, l); hi[j]=h; lo[j]=l; }
    _Float16* wf = (_Float16*)(ws + WS_WFRAG);
    *(f16x8*)&wf[((size_t)(P*4 + shi)*64 + slot)*8]     = hi;
    *(f16x8*)&wf[((size_t)(P*4 + 2 + shi)*64 + slot)*8] = lo;
  }
}

// argmin v5: 256 blocks x 512 threads (8 waves = rg2 x cg4), 128 rows/block.
// B-frags loaded straight from the global frag image (L2-resident, L1 reuse
// between rg-partner waves). NO barriers / NO LDS in the K-loop.
__global__ __launch_bounds__(512) void argmin_kernel(const float* __restrict__ xg,
                                                     float* __restrict__ out,
                                                     float* __restrict__ ws) {
  __shared__ __align__(16) _Float16 xp[8*4*64*8];   // 32 KB, X frags (negated)
  __shared__ float md[128*4];
  __shared__ int   mk[128*4];

  const int t    = threadIdx.x;
  const int lane = t & 63, wv = t >> 6;
  const int quad = lane >> 4, n16 = lane & 15;
  const int rg = wv >> 2, cg = wv & 3;
  const int row0 = blockIdx.x * 128;
  const _Float16* __restrict__ wfrag = (const _Float16*)(ws + WS_WFRAG);
  const float* __restrict__ w2hg = ws + WS_W2H;

  // ---- prologue: convert X tile (NEGATED) into fragment layout ----
#pragma unroll
  for (int it = 0; it < 2; ++it) {
    const int u  = t + 512*it;          // < 1024 granules
    const int rp = u >> 7, n = (u >> 3) & 15, g = u & 7;
    const float* src = xg + (size_t)(row0 + rp*16 + n)*64 + g*8;
    float4 v0 = *(const float4*)src, v1 = *(const float4*)(src + 4);
    float vv[8] = {v0.x,v0.y,v0.z,v0.w,v1.x,v1.y,v1.z,v1.w};
    f16x8 hi, lo;
#pragma unroll
    for (int j = 0; j < 8; ++j) { _Float16 h, l; split_f16(-vv[j], h, l); hi[j]=h; lo[j]=l; }
    const int slot = (g&3)*16 + n, shi = g >> 2;
    *(f16x8*)&xp[(((rp*4) + shi)*64 + slot)*8]     = hi;
    *(f16x8*)&xp[(((rp*4) + 2 + shi)*64 + slot)*8] = lo;
  }
  __syncthreads();

  // A-frags resident: this wave's 64-row half (rg), 64 VGPRs
  f16x8 a[4][4];
#pragma unroll
  for (int rt = 0; rt < 4; ++rt)
#pragma unroll
    for (int s = 0; s < 4; ++s)
      a[rt][s] = *(const f16x8*)&xp[(((rg*4+rt)*4 + s)*64 + lane)*8];

  float best[16]; int bestk[16];
#pragma unroll
  for (int i = 0; i < 16; ++i) { best[i] = INFINITY; bestk[i] = 0; }

  // ---- K-loop: 128 iters of 16 codes (slice cg, stride 64), no barriers ----
  const size_t lane8 = (size_t)lane * 8;
  f16x8 b0, b1, b2, b3;
  float w2;
  {
    const size_t base = ((size_t)(cg*4) * 64) * 8 + lane8;
    b0 = *(const f16x8*)&wfrag[base];
    b1 = *(const f16x8*)&wfrag[base + 512];    // s stride = 64*8
    b2 = *(const f16x8*)&wfrag[base + 1024];
    b3 = *(const f16x8*)&wfrag[base + 1536];
    w2 = w2hg[cg*16 + n16];
  }

  for (int it = 0; it < 128; ++it) {
    f16x8 n0, n1, n2, n3;
    float w2n;
    if (it < 127) {   // register-double-buffered prefetch from L2
      const size_t base = ((size_t)((it+1)*4 + cg) * 4 * 64) * 8 + lane8;
      n0 = *(const f16x8*)&wfrag[base];
      n1 = *(const f16x8*)&wfrag[base + 512];
      n2 = *(const f16x8*)&wfrag[base + 1024];
      n3 = *(const f16x8*)&wfrag[base + 1536];
      w2n = w2hg[(it+1)*64 + cg*16 + n16];
    }

    const f32x4 cin = {w2, w2, w2, w2};
    f32x4 acc[4];
    // acc = w2h + sum of (-x)*w products (8 terms), rt-interleaved
#pragma unroll
    for (int rt = 0; rt < 4; ++rt) acc[rt] = __builtin_amdgcn_mfma_f32_16x16x32_f16(a[rt][0], b0, cin, 0,0,0);
#pragma unroll
    for (int rt = 0; rt < 4; ++rt) acc[rt] = __builtin_amdgcn_mfma_f32_16x16x32_f16(a[rt][1], b1, acc[rt], 0,0,0);
#pragma unroll
    for (int rt = 0; rt < 4; ++rt) acc[rt] = __builtin_amdgcn_mfma_f32_16x16x32_f16(a[rt][2], b0, acc[rt], 0,0,0);
#pragma unroll
    for (int rt = 0; rt < 4; ++rt) acc[rt] = __builtin_amdgcn_mfma_f32_16x16x32_f16(a[rt][3], b1, acc[rt], 0,0,0);
#pragma unroll
    for (int rt = 0; rt < 4; ++rt) acc[rt] = __builtin_amdgcn_mfma_f32_16x16x32_f16(a[rt][0], b2, acc[rt], 0,0,0);
#pragma unroll
    for (int rt = 0; rt < 4; ++rt) acc[rt] = __builtin_amdgcn_mfma_f32_16x16x32_f16(a[rt][1], b3, acc[rt], 0,0,0);
#pragma unroll
    for (int rt = 0; rt < 4; ++rt) acc[rt] = __builtin_amdgcn_mfma_f32_16x16x32_f16(a[rt][2], b2, acc[rt], 0,0,0);
#pragma unroll
    for (int rt = 0; rt < 4; ++rt) acc[rt] = __builtin_amdgcn_mfma_f32_16x16x32_f16(a[rt][3], b3, acc[rt], 0,0,0);

    const int kk = it*64 + cg*16 + n16;   // ascending in it => lowest-k ties
#pragma unroll
    for (int rt = 0; rt < 4; ++rt)
#pragma unroll
      for (int reg = 0; reg < 4; ++reg) {
        const float dist = acc[rt][reg];
        const int bi = rt*4 + reg;
        if (dist < best[bi]) { best[bi] = dist; bestk[bi] = kk; }
      }

    b0 = n0; b1 = n1; b2 = n2; b3 = n3; w2 = w2n;
  }

  // ---- merge 16 code-lanes per quad (lexicographic (d,k)) ----
#pragma unroll
  for (int bi = 0; bi < 16; ++bi) {
    float bd = best[bi]; int bk = bestk[bi];
#pragma unroll
    for (int m = 1; m < 16; m <<= 1) {
      const float od = __shfl_xor(bd, m, 64);
      const int   ok = __shfl_xor(bk, m, 64);
      if (od < bd || (od == bd && ok < bk)) { bd = od; bk = ok; }
    }
    best[bi] = bd; bestk[bi] = bk;
  }
  if (n16 == 0) {
#pragma unroll
    for (int rt = 0; rt < 4; ++rt)
#pragma unroll
      for (int reg = 0; reg < 4; ++reg) {
        const int row = rg*64 + rt*16 + quad*4 + reg;
        md[row*4 + cg] = best[rt*4+reg];
        mk[row*4 + cg] = bestk[rt*4+reg];
      }
  }
  __syncthreads();

  if (t < 128) {
    const int row = t;
    float bd = md[row*4]; int bk = mk[row*4];
#pragma unroll
    for (int u = 1; u < 4; ++u) {
      const float d2 = md[row*4 + u]; const int k2 = mk[row*4 + u];
      if (d2 < bd || (d2 == bd && k2 < bk)) { bd = d2; bk = k2; }
    }
    out[OUT_IDX + row0 + row] = (float)bk;
    ((int*)ws)[WS_IDX + row0 + row] = bk;
    atomicAdd(&ws[WS_COUNTS + bk], 1.0f);
  }
}

// EMA segment-sum: 2M distinct-address fp32 atomics
__global__ __launch_bounds__(256) void ema_kernel(const float* __restrict__ xg,
                                                  float* __restrict__ ws) {
  const int lane = threadIdx.x & 63, wv = threadIdx.x >> 6;
  const int base = blockIdx.x * 128 + wv * 32;
  const int* idxb = (const int*)ws + WS_IDX;
#pragma unroll 4
  for (int r = 0; r < 32; ++r) {
    const int row = base + r;
    const int k = idxb[row];
    atomicAdd(&ws[WS_EMB + (size_t)k*64 + lane], xg[(size_t)row*64 + lane]);
  }
}

// stats: ONE block, no atomics
__global__ __launch_bounds__(256) void stats_kernel(const float* __restrict__ cc,
                                                    float* __restrict__ out,
                                                    float* __restrict__ ws) {
  const int t = threadIdx.x;
  float v1 = 0.0f, v2 = 0.0f;
#pragma unroll
  for (int i = 0; i < 32; ++i) {
    const int k = i*256 + t;
    const float cnt = ws[WS_COUNTS + k];
    const float ncc = __fadd_rn(__fmul_rn(DECAYF, cc[k]), __fmul_rn(OMDF, cnt));
    out[OUT_NCC + k] = ncc;
    const float p = cnt * (1.0f/32768.0f);
    v1 += ncc;
    v2 += __fmul_rn(p, logf(__fadd_rn(p, 1e-10f)));
  }
#pragma unroll
  for (int off = 32; off > 0; off >>= 1) {
    v1 += __shfl_down(v1, off);
    v2 += __shfl_down(v2, off);
  }
  __shared__ float s1[4], s2[4];
  const int lane = t & 63, wid = t >> 6;
  if (lane == 0) { s1[wid] = v1; s2[wid] = v2; }
  __syncthreads();
  if (t == 0) {
    ws[WS_N]   = (s1[0]+s1[1]) + (s1[2]+s1[3]);
    ws[WS_ENT] = (s2[0]+s2[1]) + (s2[2]+s2[3]);
  }
}

__global__ __launch_bounds__(256) void update_kernel(const float* __restrict__ ws0,
                                                     float* __restrict__ out,
                                                     float* __restrict__ ws) {
  const int e = blockIdx.x * 256 + threadIdx.x;  // < 524288
  const int k = e >> 6;
  const float nws = __fadd_rn(__fmul_rn(DECAYF, ws0[e]), __fmul_rn(OMDF, ws[WS_EMB + e]));
  out[OUT_NWS + e] = nws;
  const float n = ws[WS_N];
  const float ncc = out[OUT_NCC + k];
  const float smoothed = __fmul_rn(__fadd_rn(ncc, 1e-5f) / __fadd_rn(n, 0.08192f), n);
  out[OUT_NW + e] = nws / smoothed;
  if (e == 0) out[OUT_PERP] = expf(-ws[WS_ENT]);
}

// quant: per-block partials to distinct slots (WS_COUNTS reused post-stats)
__global__ __launch_bounds__(256) void quant_kernel(const float* __restrict__ xg,
                                                    float* __restrict__ out,
                                                    float* __restrict__ ws) {
  const int t = threadIdx.x;
  const int* idxb = (const int*)ws + WS_IDX;
  float v = 0.0f;
#pragma unroll
  for (int j = 0; j < 4; ++j) {
    const int e4 = (j*512 + blockIdx.x)*256 + t;   // float4 index, coalesced
    const int row = e4 >> 4, d = (e4 & 15) * 4;
    const int k = idxb[row];
    const float* nw = out + OUT_NW + (size_t)k*64 + d;
    float2 q0 = *(const float2*)nw, q1 = *(const float2*)(nw + 2);
    float4 x = *(const float4*)(xg + (size_t)e4*4);
    float qv[4] = {q0.x, q0.y, q1.x, q1.y};
    float xv[4] = {x.x, x.y, x.z, x.w};
    float4 o;
    float ov[4];
#pragma unroll
    for (int i = 0; i < 4; ++i) {
      const float df = __fsub_rn(qv[i], xv[i]);
      ov[i] = __fadd_rn(xv[i], df);
      v = fmaf(df, df, v);
    }
    o.x = ov[0]; o.y = ov[1]; o.z = ov[2]; o.w = ov[3];
    *(float4*)(out + OUT_Q + (size_t)e4*4) = o;
  }
#pragma unroll
  for (int off = 32; off > 0; off >>= 1) v += __shfl_down(v, off);
  __shared__ float sm[4];
  const int lane = t & 63, wid = t >> 6;
  if (lane == 0) sm[wid] = v;
  __syncthreads();
  if (t == 0) ws[WS_COUNTS + blockIdx.x] = (sm[0]+sm[1]) + (sm[2]+sm[3]);
}

__global__ void final_kernel(float* __restrict__ out, const float* __restrict__ ws) {
  const int t = threadIdx.x;   // 64 threads
  float v = 0.0f;
#pragma unroll
  for (int i = 0; i < 8; ++i) v += ws[WS_COUNTS + i*64 + t];
#pragma unroll
  for (int off = 32; off > 0; off >>= 1) v += __shfl_down(v, off);
  if (t == 0) out[OUT_LOSS] = __fmul_rn(0.25f, v / 2097152.0f);
}

extern "C" void kernel_launch(void* const* d_in, const int* in_sizes, int n_in,
                              void* d_out, int out_size, void* d_ws, size_t ws_size,
                              hipStream_t stream) {
  (void)in_sizes; (void)n_in; (void)out_size; (void)ws_size;
  const float* x   = (const float*)d_in[0];
  const float* w   = (const float*)d_in[1];
  const float* cc  = (const float*)d_in[2];
  const float* ws0 = (const float*)d_in[3];
  float* out = (float*)d_out;
  float* ws  = (float*)d_ws;

  hipMemsetAsync(d_ws, 0, (size_t)WS_ZERO_UNITS * 4, stream);
  hipLaunchKernelGGL(prep_kernel,   dim3(288),  dim3(256), 0, stream, w, ws);
  hipLaunchKernelGGL(argmin_kernel, dim3(256),  dim3(512), 0, stream, x, out, ws);
  hipLaunchKernelGGL(ema_kernel,    dim3(256),  dim3(256), 0, stream, x, ws);
  hipLaunchKernelGGL(stats_kernel,  dim3(1),    dim3(256), 0, stream, cc, out, ws);
  hipLaunchKernelGGL(update_kernel, dim3(2048), dim3(256), 0, stream, ws0, out, ws);
  hipLaunchKernelGGL(quant_kernel,  dim3(512),  dim3(256), 0, stream, x, out, ws);
  hipLaunchKernelGGL(final_kernel,  dim3(1),    dim3(64),  0, stream, out, ws);
}

// Round 6
// 187.788 us; speedup vs baseline: 2.2246x; 1.1243x over previous
//
#include <hip/hip_runtime.h>
#include <math.h>

typedef _Float16 f16x8 __attribute__((ext_vector_type(8)));
typedef float f32x4 __attribute__((ext_vector_type(4)));

// Problem constants
#define NROWS 32768   // 8*4096 input rows
#define KEMB  8192    // codebook entries
// DIM = 64

#define DECAYF 0.99f
#define OMDF   0.01f

// d_out layout (floats), reference return order
#define OUT_Q    0          // quantized, 2097152
#define OUT_LOSS 2097152    // vq_loss, 1
#define OUT_IDX  2097153    // idx (as float), 32768
#define OUT_PERP 2129921    // perplexity, 1
#define OUT_NW   2129922    // new_weight, 524288
#define OUT_NCC  2654210    // new_cc, 8192
#define OUT_NWS  2662402    // new_ws, 524288

// d_ws layout (4-byte units)
#define WS_N      0
#define WS_ENT    1
#define WS_COUNTS 4                    // 8192 floats (argmin atomics; reused as quant partials)
#define WS_EMB    8196                 // 524288 floats (atomic)
#define WS_IDX    532484               // 32768 ints
#define WS_W2H    565252               // 8192 floats (= ||w||^2 / 2)
#define WS_WFRAG  573444               // 524288 f32 units = 2 MB f16 frag image
#define WS_ZERO_UNITS 532484           // scalars+counts+emb

__device__ __forceinline__ float sq_rn(float v) { return __fmul_rn(v, v); }

// numpy pairwise_sum order for 64 contiguous squared values
__device__ __forceinline__ float npsumsq64(const float* vbuf) {
  float a[8];
#pragma unroll
  for (int j = 0; j < 8; ++j) a[j] = sq_rn(vbuf[j]);
#pragma unroll
  for (int m = 1; m < 8; ++m)
#pragma unroll
    for (int j = 0; j < 8; ++j) a[j] = __fadd_rn(a[j], sq_rn(vbuf[m*8 + j]));
  return __fadd_rn(__fadd_rn(__fadd_rn(a[0],a[1]), __fadd_rn(a[2],a[3])),
                   __fadd_rn(__fadd_rn(a[4],a[5]), __fadd_rn(a[6],a[7])));
}

// split a float into (hi, lo) fp16 pair; hi+lo reproduces x to ~22 bits
__device__ __forceinline__ void split_f16(float x, _Float16& hi, _Float16& lo) {
  hi = (_Float16)x;
  float r = __fsub_rn(x, (float)hi);   // exact (Sterbenz)
  lo = (_Float16)r;
}

// prep: w2h[k] = 0.5*||w_k||^2 (numpy order), W -> fragment-image f16 hi/lo.
// Image layout: frag(panel P, s, lane l) at wf[((P*4+s)*64+l)*8 .. +8];
// s=0,1 hi (K 0..31 / 32..63), s=2,3 lo. A per-lane dwordx4 load IS a B-frag.
__global__ __launch_bounds__(256) void prep_kernel(const float* __restrict__ wg,
                                                   float* __restrict__ ws) {
  const int tid = blockIdx.x * 256 + threadIdx.x;
  if (tid < KEMB) {
    const float* src = wg + (size_t)tid * 64;
    float vbuf[64];
#pragma unroll
    for (int f = 0; f < 16; ++f) {
      float4 v = *(const float4*)(src + f*4);
      vbuf[f*4+0]=v.x; vbuf[f*4+1]=v.y; vbuf[f*4+2]=v.z; vbuf[f*4+3]=v.w;
    }
    ws[WS_W2H + tid] = __fmul_rn(0.5f, npsumsq64(vbuf));
  } else if (tid < KEMB + 65536) {
    const int u = tid - KEMB;            // granule: code K, dims g*8..g*8+7
    const int K = u >> 3, g = u & 7;
    const int n = K & 15, P = K >> 4;    // global panel 0..511
    const int slot = (g&3)*16 + n, shi = g >> 2;
    const float* src = wg + (size_t)K*64 + g*8;
    float4 v0 = *(const float4*)src, v1 = *(const float4*)(src + 4);
    float vv[8] = {v0.x,v0.y,v0.z,v0.w,v1.x,v1.y,v1.z,v1.w};
    f16x8 hi, lo;
#pragma unroll
    for (int j = 0; j < 8; ++j) { _Float16 h, l; split_f16(vv[j], h, l); hi[j]=h; lo[j]=l; }
    _Float16* wf = (_Float16*)(ws + WS_WFRAG);
    *(f16x8*)&wf[((size_t)(P*4 + shi)*64 + slot)*8]     = hi;
    *(f16x8*)&wf[((size_t)(P*4 + 2 + shi)*64 + slot)*8] = lo;
  }
}

// one 16-code panel: 6 MFMA groups (lo_x*lo_w dropped; ~1.5e-6 term vs the
// ~1e-5 reassociation noise already verified flip-free on this dataset)
#define COMPUTE_PANEL(I, B0, B1, B2, B3, W2)                                        \
  {                                                                                 \
    const f32x4 cin = {(W2), (W2), (W2), (W2)};                                     \
    f32x4 acc[4];                                                                   \
    _Pragma("unroll")                                                               \
    for (int rt = 0; rt < 4; ++rt) acc[rt] = __builtin_amdgcn_mfma_f32_16x16x32_f16(a[rt][0], (B0), cin, 0,0,0); \
    _Pragma("unroll")                                                               \
    for (int rt = 0; rt < 4; ++rt) acc[rt] = __builtin_amdgcn_mfma_f32_16x16x32_f16(a[rt][1], (B1), acc[rt], 0,0,0); \
    _Pragma("unroll")                                                               \
    for (int rt = 0; rt < 4; ++rt) acc[rt] = __builtin_amdgcn_mfma_f32_16x16x32_f16(a[rt][2], (B0), acc[rt], 0,0,0); \
    _Pragma("unroll")                                                               \
    for (int rt = 0; rt < 4; ++rt) acc[rt] = __builtin_amdgcn_mfma_f32_16x16x32_f16(a[rt][3], (B1), acc[rt], 0,0,0); \
    _Pragma("unroll")                                                               \
    for (int rt = 0; rt < 4; ++rt) acc[rt] = __builtin_amdgcn_mfma_f32_16x16x32_f16(a[rt][0], (B2), acc[rt], 0,0,0); \
    _Pragma("unroll")                                                               \
    for (int rt = 0; rt < 4; ++rt) acc[rt] = __builtin_amdgcn_mfma_f32_16x16x32_f16(a[rt][1], (B3), acc[rt], 0,0,0); \
    const int kk = (I)*64 + cg*16 + n16;                                            \
    _Pragma("unroll")                                                               \
    for (int rt = 0; rt < 4; ++rt)                                                  \
      _Pragma("unroll")                                                             \
      for (int reg = 0; reg < 4; ++reg) {                                           \
        const float dist = acc[rt][reg];                                            \
        const int bi = rt*4 + reg;                                                  \
        if (dist < best[bi]) { best[bi] = dist; bestk[bi] = kk; }                   \
      }                                                                             \
  }

#define LOADB(I, C0, C1, C2, C3, CW)                                                \
  {                                                                                 \
    const size_t base = ((size_t)((I)*4 + cg) * 256) * 8 + lane8;                   \
    C0 = *(const f16x8*)&wfrag[base];                                               \
    C1 = *(const f16x8*)&wfrag[base + 512];                                         \
    C2 = *(const f16x8*)&wfrag[base + 1024];                                        \
    C3 = *(const f16x8*)&wfrag[base + 1536];                                        \
    CW = w2hg[(I)*64 + cg*16 + n16];                                                \
  }

// argmin v6: 256 blocks x 512 threads (8 waves = rg2 x cg4), 128 rows/block.
// B-frags from the global frag image (L2-resident); no barriers/LDS in K-loop;
// explicit unroll-2 double-buffer (no register rotation). EMA atomics fused.
__global__ __launch_bounds__(512) void argmin_kernel(const float* __restrict__ xg,
                                                     float* __restrict__ out,
                                                     float* __restrict__ ws) {
  __shared__ __align__(16) _Float16 xp[8*4*64*8];   // 32 KB, X frags (negated)
  __shared__ float md[128*4];
  __shared__ int   mk[128*4];
  __shared__ int   bkL[128];

  const int t    = threadIdx.x;
  const int lane = t & 63, wv = t >> 6;
  const int quad = lane >> 4, n16 = lane & 15;
  const int rg = wv >> 2, cg = wv & 3;
  const int row0 = blockIdx.x * 128;
  const _Float16* __restrict__ wfrag = (const _Float16*)(ws + WS_WFRAG);
  const float* __restrict__ w2hg = ws + WS_W2H;

  // ---- prologue: convert X tile (NEGATED) into fragment layout ----
#pragma unroll
  for (int it = 0; it < 2; ++it) {
    const int u  = t + 512*it;          // < 1024 granules
    const int rp = u >> 7, n = (u >> 3) & 15, g = u & 7;
    const float* src = xg + (size_t)(row0 + rp*16 + n)*64 + g*8;
    float4 v0 = *(const float4*)src, v1 = *(const float4*)(src + 4);
    float vv[8] = {v0.x,v0.y,v0.z,v0.w,v1.x,v1.y,v1.z,v1.w};
    f16x8 hi, lo;
#pragma unroll
    for (int j = 0; j < 8; ++j) { _Float16 h, l; split_f16(-vv[j], h, l); hi[j]=h; lo[j]=l; }
    const int slot = (g&3)*16 + n, shi = g >> 2;
    *(f16x8*)&xp[(((rp*4) + shi)*64 + slot)*8]     = hi;
    *(f16x8*)&xp[(((rp*4) + 2 + shi)*64 + slot)*8] = lo;
  }
  __syncthreads();

  // A-frags resident: this wave's 64-row half (rg), 64 VGPRs
  f16x8 a[4][4];
#pragma unroll
  for (int rt = 0; rt < 4; ++rt)
#pragma unroll
    for (int s = 0; s < 4; ++s)
      a[rt][s] = *(const f16x8*)&xp[(((rg*4+rt)*4 + s)*64 + lane)*8];

  float best[16]; int bestk[16];
#pragma unroll
  for (int i = 0; i < 16; ++i) { best[i] = INFINITY; bestk[i] = 0; }

  const size_t lane8 = (size_t)lane * 8;
  f16x8 p0, p1, p2, p3, q0, q1, q2, q3;
  float pw, qw;
  LOADB(0, p0, p1, p2, p3, pw);

  for (int it = 0; it < 128; it += 2) {
    LOADB(it+1, q0, q1, q2, q3, qw);
    COMPUTE_PANEL(it, p0, p1, p2, p3, pw);
    if (it + 2 < 128) LOADB(it+2, p0, p1, p2, p3, pw);
    COMPUTE_PANEL(it+1, q0, q1, q2, q3, qw);
  }

  // ---- merge 16 code-lanes per quad (lexicographic (d,k)) ----
#pragma unroll
  for (int bi = 0; bi < 16; ++bi) {
    float bd = best[bi]; int bk = bestk[bi];
#pragma unroll
    for (int m = 1; m < 16; m <<= 1) {
      const float od = __shfl_xor(bd, m, 64);
      const int   ok = __shfl_xor(bk, m, 64);
      if (od < bd || (od == bd && ok < bk)) { bd = od; bk = ok; }
    }
    best[bi] = bd; bestk[bi] = bk;
  }
  if (n16 == 0) {
#pragma unroll
    for (int rt = 0; rt < 4; ++rt)
#pragma unroll
      for (int reg = 0; reg < 4; ++reg) {
        const int row = rg*64 + rt*16 + quad*4 + reg;
        md[row*4 + cg] = best[rt*4+reg];
        mk[row*4 + cg] = bestk[rt*4+reg];
      }
  }
  __syncthreads();

  if (t < 128) {
    const int row = t;
    float bd = md[row*4]; int bk = mk[row*4];
#pragma unroll
    for (int u = 1; u < 4; ++u) {
      const float d2 = md[row*4 + u]; const int k2 = mk[row*4 + u];
      if (d2 < bd || (d2 == bd && k2 < bk)) { bd = d2; bk = k2; }
    }
    out[OUT_IDX + row0 + row] = (float)bk;
    ((int*)ws)[WS_IDX + row0 + row] = bk;
    bkL[row] = bk;
    atomicAdd(&ws[WS_COUNTS + bk], 1.0f);
  }
  __syncthreads();

  // ---- fused EMA segment-sum: 8 waves x 16 rows, lane = dim ----
#pragma unroll 4
  for (int r = 0; r < 16; ++r) {
    const int row = wv*16 + r;
    const int k = bkL[row];
    atomicAdd(&ws[WS_EMB + (size_t)k*64 + lane],
              xg[(size_t)(row0 + row)*64 + lane]);
  }
}

// stats: ONE block, no atomics
__global__ __launch_bounds__(256) void stats_kernel(const float* __restrict__ cc,
                                                    float* __restrict__ out,
                                                    float* __restrict__ ws) {
  const int t = threadIdx.x;
  float v1 = 0.0f, v2 = 0.0f;
#pragma unroll
  for (int i = 0; i < 32; ++i) {
    const int k = i*256 + t;
    const float cnt = ws[WS_COUNTS + k];
    const float ncc = __fadd_rn(__fmul_rn(DECAYF, cc[k]), __fmul_rn(OMDF, cnt));
    out[OUT_NCC + k] = ncc;
    const float p = cnt * (1.0f/32768.0f);
    v1 += ncc;
    v2 += __fmul_rn(p, logf(__fadd_rn(p, 1e-10f)));
  }
#pragma unroll
  for (int off = 32; off > 0; off >>= 1) {
    v1 += __shfl_down(v1, off);
    v2 += __shfl_down(v2, off);
  }
  __shared__ float s1[4], s2[4];
  const int lane = t & 63, wid = t >> 6;
  if (lane == 0) { s1[wid] = v1; s2[wid] = v2; }
  __syncthreads();
  if (t == 0) {
    ws[WS_N]   = (s1[0]+s1[1]) + (s1[2]+s1[3]);
    ws[WS_ENT] = (s2[0]+s2[1]) + (s2[2]+s2[3]);
  }
}

// update: float4-vectorized; 512 blocks x 256 threads
__global__ __launch_bounds__(256) void update_kernel(const float* __restrict__ ws0,
                                                     float* __restrict__ out,
                                                     float* __restrict__ ws) {
  const int e4 = blockIdx.x * 256 + threadIdx.x;  // < 131072 float4s
  const int k = e4 >> 4;
  const float n = ws[WS_N];
  const float ncc = out[OUT_NCC + k];
  const float smoothed = __fmul_rn(__fadd_rn(ncc, 1e-5f) / __fadd_rn(n, 0.08192f), n);
  const float inv_s = 1.0f / smoothed;
  float4 w0 = *(const float4*)(ws0 + (size_t)e4*4);
  float4 em = *(const float4*)(ws + WS_EMB + (size_t)e4*4);
  float wv[4] = {w0.x, w0.y, w0.z, w0.w};
  float ev[4] = {em.x, em.y, em.z, em.w};
  float nwsv[4], nwv[4];
#pragma unroll
  for (int i = 0; i < 4; ++i) {
    nwsv[i] = __fadd_rn(__fmul_rn(DECAYF, wv[i]), __fmul_rn(OMDF, ev[i]));
    nwv[i]  = nwsv[i] / smoothed;   // keep exact division (reference: nws / smoothed)
  }
  (void)inv_s;
  float4 onws = {nwsv[0], nwsv[1], nwsv[2], nwsv[3]};
  float4 onw  = {nwv[0],  nwv[1],  nwv[2],  nwv[3]};
  *(float4*)(out + OUT_NWS + (size_t)e4*4) = onws;
  *(float4*)(out + OUT_NW  + (size_t)e4*4) = onw;
  if (e4 == 0) out[OUT_PERP] = expf(-ws[WS_ENT]);
}

// quant: per-block partials to distinct slots (WS_COUNTS reused post-stats)
__global__ __launch_bounds__(256) void quant_kernel(const float* __restrict__ xg,
                                                    float* __restrict__ out,
                                                    float* __restrict__ ws) {
  const int t = threadIdx.x;
  const int* idxb = (const int*)ws + WS_IDX;
  float v = 0.0f;
#pragma unroll
  for (int j = 0; j < 4; ++j) {
    const int e4 = (j*512 + blockIdx.x)*256 + t;   // float4 index, coalesced
    const int row = e4 >> 4, d = (e4 & 15) * 4;
    const int k = idxb[row];
    const float* nw = out + OUT_NW + (size_t)k*64 + d;
    float2 q0 = *(const float2*)nw, q1 = *(const float2*)(nw + 2);
    float4 x = *(const float4*)(xg + (size_t)e4*4);
    float qv[4] = {q0.x, q0.y, q1.x, q1.y};
    float xv[4] = {x.x, x.y, x.z, x.w};
    float4 o;
    float ov[4];
#pragma unroll
    for (int i = 0; i < 4; ++i) {
      const float df = __fsub_rn(qv[i], xv[i]);
      ov[i] = __fadd_rn(xv[i], df);
      v = fmaf(df, df, v);
    }
    o.x = ov[0]; o.y = ov[1]; o.z = ov[2]; o.w = ov[3];
    *(float4*)(out + OUT_Q + (size_t)e4*4) = o;
  }
#pragma unroll
  for (int off = 32; off > 0; off >>= 1) v += __shfl_down(v, off);
  __shared__ float sm[4];
  const int lane = t & 63, wid = t >> 6;
  if (lane == 0) sm[wid] = v;
  __syncthreads();
  if (t == 0) ws[WS_COUNTS + blockIdx.x] = (sm[0]+sm[1]) + (sm[2]+sm[3]);
}

__global__ void final_kernel(float* __restrict__ out, const float* __restrict__ ws) {
  const int t = threadIdx.x;   // 64 threads
  float v = 0.0f;
#pragma unroll
  for (int i = 0; i < 8; ++i) v += ws[WS_COUNTS + i*64 + t];
#pragma unroll
  for (int off = 32; off > 0; off >>= 1) v += __shfl_down(v, off);
  if (t == 0) out[OUT_LOSS] = __fmul_rn(0.25f, v / 2097152.0f);
}

extern "C" void kernel_launch(void* const* d_in, const int* in_sizes, int n_in,
                              void* d_out, int out_size, void* d_ws, size_t ws_size,
                              hipStream_t stream) {
  (void)in_sizes; (void)n_in; (void)out_size; (void)ws_size;
  const float* x   = (const float*)d_in[0];
  const float* w   = (const float*)d_in[1];
  const float* cc  = (const float*)d_in[2];
  const float* ws0 = (const float*)d_in[3];
  float* out = (float*)d_out;
  float* ws  = (float*)d_ws;

  hipMemsetAsync(d_ws, 0, (size_t)WS_ZERO_UNITS * 4, stream);
  hipLaunchKernelGGL(prep_kernel,   dim3(288),  dim3(256), 0, stream, w, ws);
  hipLaunchKernelGGL(argmin_kernel, dim3(256),  dim3(512), 0, stream, x, out, ws);
  hipLaunchKernelGGL(stats_kernel,  dim3(1),    dim3(256), 0, stream, cc, out, ws);
  hipLaunchKernelGGL(update_kernel, dim3(512),  dim3(256), 0, stream, ws0, out, ws);
  hipLaunchKernelGGL(quant_kernel,  dim3(512),  dim3(256), 0, stream, x, out, ws);
  hipLaunchKernelGGL(final_kernel,  dim3(1),    dim3(64),  0, stream, out, ws);
}